// Round 1
// 106.994 us; speedup vs baseline: 1.0068x; 1.0068x over previous
//
#include <hip/hip_runtime.h>
#include <math.h>

#define N_WIRES 8
#define N_LAYERS 6
#define NG 49          // grid per axis (frequencies |n|<=24 -> 49 samples exact)
#define NG2 (NG * NG)  // 2401

// ws layout (bytes):
//   E  : [0, 76832)        8 x 2401 floats (grid EVs, [i][a*49+b])
//   Fb : [76832, +65536)   MFMA-B-fragment-ordered f16 F (pi folded):
//        frag fid=((i*4+ntile)*2+chunk): 64 lanes x 8 f16;
//        lane q*16+n, elem j  =  F_i[k=ntile*16+n][l=chunk*32+q*8+j]
//        (zero for k>=49 or l>=52)
#define WS_E_OFF 0
#define WS_FB_OFF 76832

typedef _Float16 half8 __attribute__((ext_vector_type(8)));
typedef float f32x4 __attribute__((ext_vector_type(4)));

// ---------------------------------------------------------------------------
// Grid circuit eval, block-per-point. Rewritten exchange structure:
//   - wires i>=2 (m<=32): partner is intra-wave -> __shfl_xor, NO barrier
//   - wires i=0,1 (m=128,64) and CNOT: cross-wave -> ping-pong LDS buffers,
//     ONE barrier per exchange (next exchange's barrier protects the
//     alternate buffer against WAR; same-buffer reuse is always 2 exchanges
//     apart, separated by >=1 barrier).
// Barriers per block: 108 -> 20. Gate math unchanged (byte-identical values).
// ---------------------------------------------------------------------------
__global__ __launch_bounds__(256) void qnn_grid_lds(const float* __restrict__ w,
                                                    float* __restrict__ E) {
    __shared__ float gates[N_LAYERS * N_WIRES * 8];
    __shared__ float2 bufA[256];
    __shared__ float2 bufB[256];
    __shared__ float partial[4][8];

    const int tid = threadIdx.x;
    const int g = blockIdx.x;
    const int ga = (g * 1338) >> 16;  // g/49, exact for g < 2404
    const int gb = g - ga * NG;
    const float step = (float)(2.0 * M_PI / 49.0);

    if (tid < N_LAYERS * N_WIRES) {
        const int i = tid & 7;
        float wx = w[tid * 3 + 0], wy = w[tid * 3 + 1], wz = w[tid * 3 + 2];
        float sx, cx, sy, cy, sz, cz;
        sincosf(0.5f * wx, &sx, &cx);
        sincosf(0.5f * wy, &sy, &cy);
        sincosf(0.5f * wz, &sz, &cz);
        float A00r = cy * cx, A00i = sy * sx;
        float A01r = -sy * cx, A01i = -cy * sx;
        float A10r = sy * cx, A10i = -cy * sx;
        float A11r = cy * cx, A11i = -sy * sx;
        float U00r = A00r * cz + A00i * sz, U00i = A00i * cz - A00r * sz;
        float U01r = A01r * cz + A01i * sz, U01i = A01i * cz - A01r * sz;
        float U10r = A10r * cz - A10i * sz, U10i = A10i * cz + A10r * sz;
        float U11r = A11r * cz - A11i * sz, U11i = A11i * cz + A11r * sz;
        float V00r, V00i, V01r, V01i, V10r, V10i, V11r, V11i;
        if ((i & 1) == 0) {
            V00r = U01i; V00i = -U01r;
            V01r = U00i; V01i = -U00r;
            V10r = U11i; V10i = -U11r;
            V11r = U10i; V11i = -U10r;
        } else {
            V00r = U01r;  V00i = U01i;
            V01r = -U00r; V01i = -U00i;
            V10r = U11r;  V10i = U11i;
            V11r = -U10r; V11i = -U10i;
        }
        const float xx = (i & 1) ? (step * (float)gb) : (step * (float)ga);
        float se, ce;
        sincosf(0.5f * xx, &se, &ce);
        float* o = gates + tid * 8;
        o[0] = ce * U00r + se * V00r;  o[1] = ce * U00i + se * V00i;
        o[2] = ce * U01r + se * V01r;  o[3] = ce * U01i + se * V01i;
        o[4] = ce * U10r + se * V10r;  o[5] = ce * U10i + se * V10i;
        o[6] = ce * U11r + se * V11r;  o[7] = ce * U11i + se * V11i;
    }

    float ar = (tid == 0) ? 1.0f : 0.0f;
    float ai = 0.0f;
    __syncthreads();

    int flip = 0;
    for (int l = 0; l < N_LAYERS; ++l) {
        // --- wires 0,1: cross-wave exchange via ping-pong LDS, 1 barrier ---
        #pragma unroll
        for (int i = 0; i < 2; ++i) {
            const float* gm = gates + (l * 8 + i) * 8;
            const int p = 7 - i;
            const int m = 1 << p;
            const int bit = (tid >> p) & 1;
            float2* buf = flip ? bufB : bufA;
            flip ^= 1;
            buf[tid] = make_float2(ar, ai);
            __syncthreads();
            float2 other = buf[tid ^ m];
            float a0r = bit ? other.x : ar, a0i = bit ? other.y : ai;
            float a1r = bit ? ar : other.x, a1i = bit ? ai : other.y;
            float c0r = gm[bit * 4 + 0], c0i = gm[bit * 4 + 1];
            float c1r = gm[bit * 4 + 2], c1i = gm[bit * 4 + 3];
            float nr = c0r * a0r - c0i * a0i + c1r * a1r - c1i * a1i;
            float ni = c0r * a0i + c0i * a0r + c1r * a1i + c1i * a1r;
            ar = nr; ai = ni;
        }
        // --- wires 2..7: intra-wave exchange via shfl_xor, NO barrier ---
        #pragma unroll
        for (int i = 2; i < 8; ++i) {
            const float* gm = gates + (l * 8 + i) * 8;
            const int p = 7 - i;
            const int m = 1 << p;
            const int bit = (tid >> p) & 1;
            float otr = __shfl_xor(ar, m);
            float oti = __shfl_xor(ai, m);
            float a0r = bit ? otr : ar, a0i = bit ? oti : ai;
            float a1r = bit ? ar : otr, a1i = bit ? ai : oti;
            float c0r = gm[bit * 4 + 0], c0i = gm[bit * 4 + 1];
            float c1r = gm[bit * 4 + 2], c1i = gm[bit * 4 + 3];
            float nr = c0r * a0r - c0i * a0i + c1r * a1r - c1i * a1i;
            float ni = c0r * a0i + c0i * a0r + c1r * a1i + c1i * a1r;
            ar = nr; ai = ni;
        }
        // --- CNOT chain permutation: cross-wave, ping-pong LDS, 1 barrier ---
        {
            float2* buf = flip ? bufB : bufA;
            flip ^= 1;
            buf[tid] = make_float2(ar, ai);
            __syncthreads();
            float2 src = buf[tid ^ (tid >> 1)];
            ar = src.x; ai = src.y;
        }
    }

    float p = ar * ar + ai * ai;
    float ev[8];
    #pragma unroll
    for (int i = 0; i < 8; ++i) ev[i] = ((tid >> (7 - i)) & 1) ? -p : p;
    #pragma unroll
    for (int i = 0; i < 8; ++i) {
        #pragma unroll
        for (int s = 1; s < 64; s <<= 1) ev[i] += __shfl_xor(ev[i], s);
    }
    const int wave = tid >> 6, lane = tid & 63;
    if (lane == 0) {
        #pragma unroll
        for (int i = 0; i < 8; ++i) partial[wave][i] = ev[i];
    }
    __syncthreads();
    if (tid < 8) {
        E[tid * NG2 + g] = partial[0][tid] + partial[1][tid] + partial[2][tid] + partial[3][tid];
    }
}

// ---------------------------------------------------------------------------
// Fused separable 2D DFT writing MFMA-B-fragment-ordered f16.
// Rewritten: serial cos/sin rotation recurrence replaced with an EXACT
// mod-49 shared sincos table (step*49 = 2*pi), turning the dependent chain
// into independent FMAs. Grid (64, 8) = (kp, i); kp/l >= 49 write zeros.
// ---------------------------------------------------------------------------
__global__ __launch_bounds__(64) void dft2(const float* __restrict__ E,
                                           _Float16* __restrict__ Fb) {
    const int kp = blockIdx.x, i = blockIdx.y, t = threadIdx.x;
    __shared__ float Es[NG2];
    __shared__ float H[NG];
    __shared__ float tc[NG], ts[NG];
    const float step = (float)(2.0 * M_PI / 49.0);
    const float PI = 3.14159265358979323846f;

    if (t < NG) {
        float s, c;
        sincosf(step * (float)t, &s, &c);
        tc[t] = c; ts[t] = s;
    }
    if (kp < NG) {
        for (int e = t; e < NG2; e += 64) Es[e] = E[i * NG2 + e];
    }
    __syncthreads();

    if (kp < NG && t < NG) {
        const int b = t;
        const int n = (kp + 1) >> 1;  // 0 for kp==0
        const bool use_cos = (kp & 1) || (kp == 0);
        float acc = 0.f;
        int j = 0;
        for (int a = 0; a < NG; ++a) {
            acc = fmaf(Es[a * NG + b], use_cos ? tc[j] : ts[j], acc);
            j += n; if (j >= NG) j -= NG;
        }
        acc *= (kp == 0) ? (1.0f / 49.0f) : (2.0f / 49.0f);
        H[b] = acc;
    }
    __syncthreads();

    const int l = t;
    float acc = 0.f;
    if (kp < NG && l < NG) {
        const int n = (l + 1) >> 1;  // 0 for l==0
        const bool use_cos = (l & 1) || (l == 0);
        int j = 0;
        for (int b = 0; b < NG; ++b) {
            acc = fmaf(H[b], use_cos ? tc[j] : ts[j], acc);
            j += n; if (j >= NG) j -= NG;
        }
        acc *= (l == 0) ? (PI / 49.0f) : (2.0f * PI / 49.0f);
    }
    {
        const int ntile = kp >> 4, n = kp & 15;
        const int chunk = l >> 5, lrem = l & 31;
        const int q = lrem >> 3, j = lrem & 7;
        const int fid = (i * 4 + ntile) * 2 + chunk;
        Fb[fid * 512 + (q * 16 + n) * 8 + j] = (_Float16)acc;
    }
}

// ---------------------------------------------------------------------------
// MFMA contraction, ALL 8 OUTPUTS PER BLOCK (unchanged this round for clean
// attribution of the grid/dft2 delta).
// ---------------------------------------------------------------------------
#define V0PAD 68

__global__ __launch_bounds__(256) void contract_mfma(const float* __restrict__ x,
                                                     const _Float16* __restrict__ Fb,
                                                     float* __restrict__ out, int B) {
    __shared__ float xs0[64], xs1[64];
    __shared__ float v0t[64 * V0PAD];  // 17.4 KB

    const int tid = threadIdx.x;
    const int bbase = blockIdx.x * 64;
    if (bbase >= B) return;

    if (tid < 64) {
        float2 xv = ((const float2*)x)[bbase + tid];
        xs0[tid] = xv.x;
        xs1[tid] = xv.y;
    }
    __syncthreads();

    // ---- v0 table: thread t -> batch b=t&63, k-segment s=t>>6 (16 k's) ----
    {
        const int b = tid & 63, s = tid >> 6;
        const float x0 = xs0[b];
        float c1, s1;
        sincosf(x0, &s1, &c1);
        float cb, sb;
        sincosf((float)(8 * s) * x0, &sb, &cb);
        float* row = v0t + b * V0PAD + 16 * s;
        const int k0 = 16 * s;
        row[0] = (k0 == 0) ? 1.0f : ((k0 < NG) ? sb : 0.0f);
        float cm = cb, sm = sb;
        #pragma unroll
        for (int j = 1; j < 16; ++j) {
            if (j & 1) {
                float c2 = cm * c1 - sm * s1, s2 = sm * c1 + cm * s1;
                cm = c2; sm = s2;
            }
            float val = (j & 1) ? cm : sm;
            row[j] = ((k0 + j) < NG) ? val : 0.0f;
        }
    }

    const int lane = tid & 63;
    const int w = tid >> 6;
    const int q = lane >> 4;

    // ---- A fragments (built once, reused for all 4 i-pairs) ----
    const float x1v = xs1[w * 16 + (lane & 15)];
    float c1, s1;
    sincosf(x1v, &s1, &c1);
    half8 afrag[2];
    #pragma unroll
    for (int c = 0; c < 2; ++c) {
        const int l0 = c * 32 + q * 8;
        float cb, sb;
        sincosf((float)(l0 >> 1) * x1v, &sb, &cb);
        float vals[8];
        vals[0] = (l0 == 0) ? 1.0f : sb;
        float cm = cb, sm = sb;
        #pragma unroll
        for (int j = 1; j < 8; ++j) {
            if (j & 1) {
                float c2 = cm * c1 - sm * s1, s2 = sm * c1 + cm * s1;
                cm = c2; sm = s2;
            }
            vals[j] = (j & 1) ? cm : sm;
        }
        #pragma unroll
        for (int j = 0; j < 8; ++j) {
            afrag[c][j] = (_Float16)(((l0 + j) < 52) ? vals[j] : 0.0f);
        }
    }

    __syncthreads();  // v0t ready

    const half8* FB = (const half8*)Fb;

    #pragma unroll 1
    for (int ip = 0; ip < 4; ++ip) {
        const int i0 = ip * 2;

        // B fragments for this i-pair (L2-hot, 16 x 16B vector loads)
        half8 bfrag[16];
        #pragma unroll
        for (int ii = 0; ii < 2; ++ii)
            #pragma unroll
            for (int nt = 0; nt < 4; ++nt)
                #pragma unroll
                for (int c = 0; c < 2; ++c) {
                    const int fid = ((i0 + ii) * 4 + nt) * 2 + c;
                    bfrag[(ii * 4 + nt) * 2 + c] = FB[fid * 64 + lane];
                }

        f32x4 acc[8];
        #pragma unroll
        for (int t = 0; t < 8; ++t) {
            f32x4 z = {0.f, 0.f, 0.f, 0.f};
            acc[t] = __builtin_amdgcn_mfma_f32_16x16x32_f16(afrag[0], bfrag[t * 2 + 0], z, 0, 0, 0);
            acc[t] = __builtin_amdgcn_mfma_f32_16x16x32_f16(afrag[1], bfrag[t * 2 + 1], acc[t], 0, 0, 0);
        }

        float res[2][4];
        #pragma unroll
        for (int ii = 0; ii < 2; ++ii)
            #pragma unroll
            for (int r = 0; r < 4; ++r) res[ii][r] = 0.f;

        #pragma unroll
        for (int ii = 0; ii < 2; ++ii)
            #pragma unroll
            for (int nt = 0; nt < 4; ++nt) {
                f32x4 a = acc[ii * 4 + nt];
                #pragma unroll
                for (int r = 0; r < 4; ++r) {
                    const int bloc = w * 16 + q * 4 + r;
                    float v0 = v0t[bloc * V0PAD + nt * 16 + (lane & 15)];
                    res[ii][r] = fmaf(a[r], v0, res[ii][r]);
                }
            }

        #pragma unroll
        for (int ii = 0; ii < 2; ++ii)
            #pragma unroll
            for (int r = 0; r < 4; ++r) {
                float v = res[ii][r];
                v += __shfl_xor(v, 1);
                v += __shfl_xor(v, 2);
                v += __shfl_xor(v, 4);
                v += __shfl_xor(v, 8);
                res[ii][r] = v;
            }

        if ((lane & 15) == 0) {
            #pragma unroll
            for (int r = 0; r < 4; ++r) {
                const int b = bbase + w * 16 + q * 4 + r;
                out[(size_t)b * 8 + i0 + 0] = res[0][r];
                out[(size_t)b * 8 + i0 + 1] = res[1][r];
            }
        }
    }
}

extern "C" void kernel_launch(void* const* d_in, const int* in_sizes, int n_in,
                              void* d_out, int out_size, void* d_ws, size_t ws_size,
                              hipStream_t stream) {
    (void)n_in; (void)out_size; (void)ws_size;
    const float* x = (const float*)d_in[0];
    const float* w = (const float*)d_in[1];
    float* out = (float*)d_out;
    char* ws = (char*)d_ws;
    float* E = (float*)(ws + WS_E_OFF);
    _Float16* Fb = (_Float16*)(ws + WS_FB_OFF);
    const int B = in_sizes[0] / 2;

    hipLaunchKernelGGL(qnn_grid_lds, dim3(NG2), dim3(256), 0, stream, w, E);
    hipLaunchKernelGGL(dft2, dim3(64, 8), dim3(64), 0, stream, E, Fb);
    hipLaunchKernelGGL(contract_mfma, dim3((B + 63) / 64, 1), dim3(256), 0, stream,
                       x, Fb, out, B);
}